// Round 7
// baseline (717.149 us; speedup 1.0000x reference)
//
#include <hip/hip_runtime.h>

#define CSC 64
#define CVC 32
#define HIDC 128
#define NWC 224
#define RBFD 32
#define CUTF 5.0f

typedef __attribute__((ext_vector_type(8))) short bfrag8;
typedef __attribute__((ext_vector_type(4))) float facc4;

__device__ __forceinline__ unsigned short f2bf(float x) {
    union { float f; unsigned int u; } a; a.f = x;
    unsigned int u = a.u;
    return (unsigned short)((u + 0x7fffu + ((u >> 16) & 1u)) >> 16);
}

__device__ __forceinline__ float siluf(float x) { return x / (1.0f + __expf(-x)); }
__device__ __forceinline__ float sigmf(float x) { return 1.0f / (1.0f + __expf(-x)); }

// ---------------- CSR build ------------------------------------------------------------------
__global__ __launch_bounds__(256) void eae_zero_int(int* __restrict__ p, int n) {
    int i = blockIdx.x * 256 + threadIdx.x;
    if (i < n) p[i] = 0;
}

__global__ __launch_bounds__(256) void eae_hist_kernel(const int* __restrict__ edge_dst,
                                                       int* __restrict__ cnt, int E) {
    int e = blockIdx.x * 256 + threadIdx.x;
    if (e < E) atomicAdd(&cnt[edge_dst[e]], 1);
}

__global__ __launch_bounds__(256) void eae_scan_kernel(const int* __restrict__ cnt,
                                                       int* __restrict__ row_ptr,
                                                       int* __restrict__ cursor, int BN) {
    __shared__ int part[256];
    int t = threadIdx.x;
    int per = (BN + 255) / 256;
    int base = t * per;
    int local[16];
    int lsum = 0;
    for (int i = 0; i < per; ++i) {
        int idx = base + i;
        int c = (idx < BN) ? cnt[idx] : 0;
        local[i] = c; lsum += c;
    }
    part[t] = lsum;
    __syncthreads();
    if (t == 0) {
        int run = 0;
        for (int i = 0; i < 256; ++i) { int v = part[i]; part[i] = run; run += v; }
    }
    __syncthreads();
    int run = part[t];
    for (int i = 0; i < per; ++i) {
        int idx = base + i;
        if (idx < BN) { row_ptr[idx] = run; cursor[idx] = run; run += local[i]; }
    }
    if (t == 255) row_ptr[BN] = run;
}

__global__ __launch_bounds__(256) void eae_scatter_kernel(
    const int* __restrict__ edge_dst, const int* __restrict__ edge_src,
    const float* __restrict__ edge_weight, const float* __restrict__ edge_vec,
    int* __restrict__ cursor, float4* __restrict__ edata, int* __restrict__ esrc, int E) {
    int e = blockIdx.x * 256 + threadIdx.x;
    if (e < E) {
        int pos = atomicAdd(&cursor[edge_dst[e]], 1);
        float4 d;
        d.x = edge_weight[e];
        d.y = edge_vec[3 * e + 0];
        d.z = edge_vec[3 * e + 1];
        d.w = edge_vec[3 * e + 2];
        edata[pos] = d;
        esrc[pos] = edge_src[e];
    }
}

// ---------------- weight packing: bf16 MFMA fragment layout (once per call) ------------------
__global__ __launch_bounds__(64) void eae_pack_kernel(
    const float* __restrict__ W1, const float* __restrict__ W2,
    unsigned short* __restrict__ W1P, unsigned short* __restrict__ W2P)
{
    int b = blockIdx.x;
    int lane = threadIdx.x;
    int t4 = lane >> 4, lr = lane & 15;
    if (b < 24) {
        int blk = b >> 3, mt = b & 7;
        const float* W1b = W1 + blk * 32 * 128;
        unsigned short* dst = W1P + ((size_t)b * 64 + lane) * 8;
        #pragma unroll
        for (int i = 0; i < 8; ++i) {
            int k = 8 * t4 + i;
            dst[i] = f2bf(W1b[k * HIDC + 16 * mt + lr]);
        }
    } else {
        int idx = b - 24;
        int blk = idx >> 6, rem = idx & 63;
        int mt = rem >> 2, ks = rem & 3;
        const float* W2b = W2 + blk * 128 * 224;
        unsigned short* dst = W2P + ((size_t)idx * 64 + lane) * 8;
        int ch = 16 * mt + lr;
        #pragma unroll
        for (int i = 0; i < 8; ++i) {
            int k = 32 * ks + 8 * t4 + i;
            dst[i] = (ch < NWC) ? f2bf(W2b[k * NWC + ch]) : (unsigned short)0;
        }
    }
}

// ---------------- init: s ; zero v (SoA) -----------------------------------------------------
__global__ __launch_bounds__(128) void eae_init_kernel(
    const int* __restrict__ z, const float* __restrict__ mask, const int* __restrict__ absorber,
    const float* __restrict__ z_emb, const float* __restrict__ W_in,
    float* __restrict__ s, float* __restrict__ v)
{
    int n = blockIdx.x;
    int t = threadIdx.x;
    int b = n >> 6;
    int ni = n & 63;
    float fm = mask[n];
    int zi = z[n];
    float af = (absorber[b] == ni) ? 1.0f : 0.0f;
    if (t < 64) {
        const float* ze = z_emb + zi * 64;
        float acc = 0.0f;
        #pragma unroll 4
        for (int k = 0; k < 64; ++k) acc += ze[k] * W_in[k * 64 + t];
        acc += af * W_in[64 * 64 + t];
        s[n * 64 + t] = acc * fm;
    }
    if (t < 96) v[n * 96 + t] = 0.0f;
}

// ---------------- edge kernel: 8 waves, 1 GEMM1-tile + 2 GEMM2-tiles per wave ----------------
// round-5-proven structure; ONLY change: min-waves/EU 2 -> 4 (2 blocks/CU co-resident)
__global__ __launch_bounds__(512, 4) void eae_edge_kernel(
    const int* __restrict__ row_ptr,
    const float4* __restrict__ edata, const int* __restrict__ esrc,
    const unsigned short* __restrict__ W1Pb, const float* __restrict__ b1b,
    const unsigned short* __restrict__ W2Pb, const float* __restrict__ b2b,
    const float* __restrict__ s, const float* __restrict__ v,
    float* __restrict__ aggs, float* __restrict__ aggv, int BN)
{
    __shared__ unsigned short h_lds[64 * 128];   // h[e][k] bf16, swizzled, 16KB
    char* hb = (char*)h_lds;

    const int tid  = threadIdx.x;
    const int wid  = tid >> 6;       // 0..7
    const int lane = tid & 63;
    const int t4   = lane >> 4;
    const int lr   = lane & 15;
    const int swz  = (lr & 7) << 4;

    // ---- persistent preload: W1 tile (1 per wave) + W2 tiles (2 per wave) ----
    bfrag8 a1;
    float b1v[4];
    a1 = *reinterpret_cast<const bfrag8*>(W1Pb + ((size_t)wid * 64 + lane) * 8);
    #pragma unroll
    for (int r = 0; r < 4; ++r) b1v[r] = b1b[16 * wid + 4 * t4 + r];

    bfrag8 a2[2][4];
    float b2v[2][4];
    #pragma unroll
    for (int m = 0; m < 2; ++m) {
        int mt = 2 * wid + m;
        #pragma unroll
        for (int ks = 0; ks < 4; ++ks)
            a2[m][ks] = *reinterpret_cast<const bfrag8*>(W2Pb + (((size_t)mt * 4 + ks) * 64 + lane) * 8);
        #pragma unroll
        for (int r = 0; r < 4; ++r) {
            int chr = 16 * mt + 4 * t4 + r;
            b2v[m][r] = (chr < NWC) ? b2b[chr] : 0.0f;
        }
    }

    const float delta = CUTF / (RBFD - 1);
    const float inv_delta = 1.0f / delta;
    const float SQ3 = 1.7320508075688772f;
    const float IS3 = 0.57735026918962576f;
    const float IS2 = 0.70710678118654752f;
    const float PIF = 3.14159265358979323846f;

    for (int n = blockIdx.x; n < BN; n += gridDim.x) {
        const int ebeg = row_ptr[n];
        const int ecnt = row_ptr[n + 1] - ebeg;
        const int ntile = (ecnt + 63) >> 6;

        float rA[2][4][3];
        #pragma unroll
        for (int m = 0; m < 2; ++m)
            #pragma unroll
            for (int r = 0; r < 4; ++r)
                #pragma unroll
                for (int c = 0; c < 3; ++c) rA[m][r][c] = 0.0f;

        for (int tile = 0; tile < ntile; ++tile) {
            const int e0 = tile * 64;

            int   src4[4];
            float env4[4], y4[4][3];
            bfrag8 brbf[4];
            #pragma unroll
            for (int et = 0; et < 4; ++et) {
                int el_idx = e0 + 16 * et + lr;
                bool valid = (el_idx < ecnt);
                int ie = ebeg + (valid ? el_idx : 0);
                float4 ed = edata[ie];
                float el = ed.x;
                float inv = 1.0f / fmaxf(el, 1e-8f);
                y4[et][0] = SQ3 * ed.y * inv;
                y4[et][1] = SQ3 * ed.z * inv;
                y4[et][2] = SQ3 * ed.w * inv;
                float env = (el < CUTF) ? 0.5f * (__cosf(PIF * el / CUTF) + 1.0f) : 0.0f;
                env4[et] = valid ? env : 0.0f;
                src4[et] = esrc[ie];
                float d = fminf(el, CUTF);
                bfrag8 f;
                #pragma unroll
                for (int i = 0; i < 8; ++i) {
                    int k = 8 * t4 + i;
                    float x = (d - (float)k * delta) * inv_delta;
                    f[i] = (short)f2bf(__expf(-0.5f * x * x));
                }
                brbf[et] = f;
            }

            // ---- GEMM1: one ch-tile per wave ----
            facc4 acc1[4];
            #pragma unroll
            for (int et = 0; et < 4; ++et) { facc4 zz = {0.f,0.f,0.f,0.f}; acc1[et] = zz; }
            #pragma unroll
            for (int et = 0; et < 4; ++et)
                acc1[et] = __builtin_amdgcn_mfma_f32_16x16x32_bf16(a1, brbf[et], acc1[et], 0, 0, 0);

            // ---- silu -> bf16 -> LDS h[e][ch], swizzled ----
            {
                int ch0b = (16 * wid + 4 * t4) * 2;
                #pragma unroll
                for (int et = 0; et < 4; ++et) {
                    int e = 16 * et + lr;
                    unsigned short hv[4];
                    #pragma unroll
                    for (int r = 0; r < 4; ++r)
                        hv[r] = f2bf(siluf(acc1[et][r] + b1v[r]));
                    uint2 pk;
                    pk.x = (unsigned int)hv[0] | ((unsigned int)hv[1] << 16);
                    pk.y = (unsigned int)hv[2] | ((unsigned int)hv[3] << 16);
                    *reinterpret_cast<uint2*>(hb + e * 256 + (ch0b ^ swz)) = pk;
                }
            }
            __syncthreads();

            // ---- GEMM2: two mt-tiles per wave ----
            facc4 acc2[2][4];
            #pragma unroll
            for (int m = 0; m < 2; ++m)
                #pragma unroll
                for (int et = 0; et < 4; ++et) { facc4 zz = {0.f,0.f,0.f,0.f}; acc2[m][et] = zz; }
            #pragma unroll
            for (int et = 0; et < 4; ++et) {
                int e = 16 * et + lr;
                bfrag8 hf[4];
                #pragma unroll
                for (int ks = 0; ks < 4; ++ks)
                    hf[ks] = *reinterpret_cast<const bfrag8*>(hb + e * 256 + ((64 * ks + 16 * t4) ^ swz));
                #pragma unroll
                for (int m = 0; m < 2; ++m)
                    #pragma unroll
                    for (int ks = 0; ks < 4; ++ks)
                        acc2[m][et] = __builtin_amdgcn_mfma_f32_16x16x32_bf16(a2[m][ks], hf[ks], acc2[m][et], 0, 0, 0);
            }

            // ---- epilogue: accumulate per-lane messages (butterfly deferred) ----
            #pragma unroll
            for (int m = 0; m < 2; ++m) {
                int mt = 2 * wid + m;
                if (mt < 14) {
                    if (mt < 4) {               // w_ss
                        int c0 = 16 * mt + 4 * t4;
                        #pragma unroll
                        for (int et = 0; et < 4; ++et) {
                            int src = src4[et]; float env = env4[et];
                            const float4 sv = *reinterpret_cast<const float4*>(&s[src * CSC + c0]);
                            float vals[4] = {sv.x, sv.y, sv.z, sv.w};
                            #pragma unroll
                            for (int r = 0; r < 4; ++r) {
                                float w = (acc2[m][et][r] + b2v[m][r]) * env;
                                rA[m][r][0] += w * vals[r];
                            }
                        }
                    } else if (mt < 6) {        // w_vv
                        int c0 = 16 * (mt - 4) + 4 * t4;
                        #pragma unroll
                        for (int et = 0; et < 4; ++et) {
                            int src = src4[et]; float env = env4[et];
                            float yx = y4[et][0], yy = y4[et][1], yz = y4[et][2];
                            const float* vb = &v[src * 96];
                            const float4 vx4 = *reinterpret_cast<const float4*>(vb + c0);
                            const float4 vy4 = *reinterpret_cast<const float4*>(vb + 32 + c0);
                            const float4 vz4 = *reinterpret_cast<const float4*>(vb + 64 + c0);
                            float ax[4] = {vx4.x, vx4.y, vx4.z, vx4.w};
                            float ay[4] = {vy4.x, vy4.y, vy4.z, vy4.w};
                            float az[4] = {vz4.x, vz4.y, vz4.z, vz4.w};
                            #pragma unroll
                            for (int r = 0; r < 4; ++r) {
                                float dp = ax[r] * yx + ay[r] * yy + az[r] * yz;
                                float w = (acc2[m][et][r] + b2v[m][r]) * env;
                                rA[m][r][0] += w * dp * IS3;
                            }
                        }
                    } else if (mt < 10) {       // w_sv
                        int c0 = 16 * (mt - 6) + 4 * t4;
                        #pragma unroll
                        for (int et = 0; et < 4; ++et) {
                            int src = src4[et]; float env = env4[et];
                            float yx = y4[et][0], yy = y4[et][1], yz = y4[et][2];
                            const float4 sv = *reinterpret_cast<const float4*>(&s[src * CSC + c0]);
                            float vals[4] = {sv.x, sv.y, sv.z, sv.w};
                            #pragma unroll
                            for (int r = 0; r < 4; ++r) {
                                float wv = (acc2[m][et][r] + b2v[m][r]) * env * vals[r];
                                rA[m][r][0] += wv * yx;
                                rA[m][r][1] += wv * yy;
                                rA[m][r][2] += wv * yz;
                            }
                        }
                    } else if (mt < 12) {       // w_vs
                        int c0 = 16 * (mt - 10) + 4 * t4;
                        #pragma unroll
                        for (int et = 0; et < 4; ++et) {
                            int src = src4[et]; float env = env4[et];
                            const float* vb = &v[src * 96];
                            const float4 vx4 = *reinterpret_cast<const float4*>(vb + c0);
                            const float4 vy4 = *reinterpret_cast<const float4*>(vb + 32 + c0);
                            const float4 vz4 = *reinterpret_cast<const float4*>(vb + 64 + c0);
                            float ax[4] = {vx4.x, vx4.y, vx4.z, vx4.w};
                            float ay[4] = {vy4.x, vy4.y, vy4.z, vy4.w};
                            float az[4] = {vz4.x, vz4.y, vz4.z, vz4.w};
                            #pragma unroll
                            for (int r = 0; r < 4; ++r) {
                                float w = (acc2[m][et][r] + b2v[m][r]) * env;
                                rA[m][r][0] += w * ax[r];
                                rA[m][r][1] += w * ay[r];
                                rA[m][r][2] += w * az[r];
                            }
                        }
                    } else {                    // w_vx (cross)
                        int c0 = 16 * (mt - 12) + 4 * t4;
                        #pragma unroll
                        for (int et = 0; et < 4; ++et) {
                            int src = src4[et]; float env = env4[et];
                            float yx = y4[et][0], yy = y4[et][1], yz = y4[et][2];
                            const float* vb = &v[src * 96];
                            const float4 vx4 = *reinterpret_cast<const float4*>(vb + c0);
                            const float4 vy4 = *reinterpret_cast<const float4*>(vb + 32 + c0);
                            const float4 vz4 = *reinterpret_cast<const float4*>(vb + 64 + c0);
                            float ax[4] = {vx4.x, vx4.y, vx4.z, vx4.w};
                            float ay[4] = {vy4.x, vy4.y, vy4.z, vy4.w};
                            float az[4] = {vz4.x, vz4.y, vz4.z, vz4.w};
                            #pragma unroll
                            for (int r = 0; r < 4; ++r) {
                                float ww = (acc2[m][et][r] + b2v[m][r]) * env * IS2;
                                rA[m][r][0] += ww * (ay[r] * yz - az[r] * yy);
                                rA[m][r][1] += ww * (az[r] * yx - ax[r] * yz);
                                rA[m][r][2] += ww * (ax[r] * yy - ay[r] * yx);
                            }
                        }
                    }
                }
            }
            __syncthreads();   // protect h_lds before next tile
        }

        // ---- butterfly over lr lanes (once per node), then store ----
        #pragma unroll
        for (int m = 0; m < 2; ++m)
            #pragma unroll
            for (int r = 0; r < 4; ++r)
                #pragma unroll
                for (int c = 0; c < 3; ++c) {
                    float x = rA[m][r][c];
                    x += __shfl_xor(x, 1);
                    x += __shfl_xor(x, 2);
                    x += __shfl_xor(x, 4);
                    x += __shfl_xor(x, 8);
                    rA[m][r][c] = x;
                }

        if (lr == 0) {
            #pragma unroll
            for (int m = 0; m < 2; ++m) {
                int mt = 2 * wid + m;
                if (mt < 4) {
                    int c0 = 16 * mt + 4 * t4;
                    #pragma unroll
                    for (int r = 0; r < 4; ++r) aggs[n * 96 + c0 + r] = rA[m][r][0];
                } else if (mt < 6) {
                    int c0 = 16 * (mt - 4) + 4 * t4;
                    #pragma unroll
                    for (int r = 0; r < 4; ++r) aggs[n * 96 + 64 + c0 + r] = rA[m][r][0];
                } else if (mt < 10) {
                    int c0 = 16 * (mt - 6) + 4 * t4;           // aggv SoA [3][128]
                    #pragma unroll
                    for (int r = 0; r < 4; ++r)
                        #pragma unroll
                        for (int c = 0; c < 3; ++c)
                            aggv[n * 384 + c * 128 + c0 + r] = rA[m][r][c];
                } else if (mt < 12) {
                    int c0 = 16 * (mt - 10) + 4 * t4;
                    #pragma unroll
                    for (int r = 0; r < 4; ++r)
                        #pragma unroll
                        for (int c = 0; c < 3; ++c)
                            aggv[n * 384 + c * 128 + 64 + c0 + r] = rA[m][r][c];
                } else if (mt < 14) {
                    int c0 = 16 * (mt - 12) + 4 * t4;
                    #pragma unroll
                    for (int r = 0; r < 4; ++r)
                        #pragma unroll
                        for (int c = 0; c < 3; ++c)
                            aggv[n * 384 + c * 128 + 96 + c0 + r] = rA[m][r][c];
                }
            }
        }
    }
}

// ---------------- node update (SoA v/aggv) ---------------------------------------------------
__global__ __launch_bounds__(128) void eae_node_kernel(
    const float* __restrict__ Ws, const float* __restrict__ Wv, const float* __restrict__ Wg,
    const float* __restrict__ alpha,
    float* __restrict__ s, float* __restrict__ v,
    const float* __restrict__ aggs, const float* __restrict__ aggv, int blk)
{
    int n = blockIdx.x;
    int t = threadIdx.x;
    __shared__ float sh_as[96];
    __shared__ float sh_av[384];
    __shared__ float sh_us[64];
    __shared__ float sh_g[32];

    for (int i = t; i < 96; i += 128) sh_as[i] = aggs[n * 96 + i];
    for (int i = t; i < 384; i += 128) sh_av[i] = aggv[n * 384 + i];
    __syncthreads();

    float a = alpha[blk];
    const float* Wsb = Ws + blk * 96 * 64;
    const float* Wvb = Wv + blk * 128 * 32;
    const float* Wgb = Wg + blk * 64 * 32;

    if (t < 64) {
        float acc = 0.0f;
        #pragma unroll 4
        for (int j = 0; j < 96; ++j) acc += sh_as[j] * Wsb[j * 64 + t];
        sh_us[t] = siluf(acc);
    }
    __syncthreads();
    if (t < 32) {
        float acc = 0.0f;
        #pragma unroll 4
        for (int j = 0; j < 64; ++j) acc += sh_us[j] * Wgb[j * 32 + t];
        sh_g[t] = sigmf(acc);
    }
    if (t < 64) s[n * 64 + t] += a * sh_us[t];
    __syncthreads();
    if (t < 96) {
        int d = t >> 5;
        int c = t & 31;
        float acc = 0.0f;
        #pragma unroll 4
        for (int j = 0; j < 128; ++j) acc += sh_av[d * 128 + j] * Wvb[j * 32 + c];
        v[n * 96 + d * 32 + c] += a * sh_g[c] * acc;
    }
}

// ---------------- final: IrrepNorm + mask + pack output --------------------------------------
__global__ __launch_bounds__(64) void eae_final_kernel(
    const float* __restrict__ mask, const float* __restrict__ s, const float* __restrict__ v,
    float* __restrict__ out)
{
    int n = blockIdx.x;
    int t = threadIdx.x;
    float fm = mask[n];

    float sv = s[n * 64 + t];
    float ss = sv * sv;
    #pragma unroll
    for (int o = 32; o >= 1; o >>= 1) ss += __shfl_xor(ss, o);
    float sn = sv / sqrtf(ss / 64.0f + 1e-6f);
    out[n * 160 + t] = sn * fm;

    float vx = (t < 32) ? v[n * 96 + t]      : 0.0f;
    float vy = (t < 32) ? v[n * 96 + 32 + t] : 0.0f;
    float vz = (t < 32) ? v[n * 96 + 64 + t] : 0.0f;
    float vs2 = vx * vx + vy * vy + vz * vz;
    #pragma unroll
    for (int o = 32; o >= 1; o >>= 1) vs2 += __shfl_xor(vs2, o);
    float scale = fm / sqrtf(vs2 / 32.0f + 1e-6f);
    if (t < 32) {
        out[n * 160 + 64 + t * 3 + 0] = vx * scale;
        out[n * 160 + 64 + t * 3 + 1] = vy * scale;
        out[n * 160 + 64 + t * 3 + 2] = vz * scale;
    }
}

extern "C" void kernel_launch(void* const* d_in, const int* in_sizes, int n_in,
                              void* d_out, int out_size, void* d_ws, size_t ws_size,
                              hipStream_t stream) {
    const int*   z           = (const int*)d_in[0];
    const float* mask        = (const float*)d_in[1];
    const int*   absorber    = (const int*)d_in[2];
    const int*   edge_src    = (const int*)d_in[3];
    const int*   edge_dst    = (const int*)d_in[4];
    const float* edge_weight = (const float*)d_in[5];
    const float* edge_vec    = (const float*)d_in[6];
    const float* z_emb       = (const float*)d_in[7];
    const float* W_in        = (const float*)d_in[8];
    const float* W1          = (const float*)d_in[9];
    const float* b1          = (const float*)d_in[10];
    const float* W2          = (const float*)d_in[11];
    const float* b2          = (const float*)d_in[12];
    const float* Ws          = (const float*)d_in[13];
    const float* Wv          = (const float*)d_in[14];
    const float* Wg          = (const float*)d_in[15];
    const float* alpha       = (const float*)d_in[16];
    float* out = (float*)d_out;

    const int BN = in_sizes[0];    // 2048
    const int E  = in_sizes[3];    // 131072

    float* ws_f = (float*)d_ws;
    float4* edata = (float4*)ws_f;                       // E float4
    float* s    = ws_f + (size_t)E * 4;                  // BN*64
    float* v    = s + (size_t)BN * 64;                   // BN*96  SoA [3][32]
    float* aggs = v + (size_t)BN * 96;                   // BN*96
    float* aggv = aggs + (size_t)BN * 96;                // BN*384 SoA [3][128]
    int*   iws  = (int*)(aggv + (size_t)BN * 384);
    int* esrc    = iws;                                  // E
    int* cnt     = esrc + E;                             // BN
    int* row_ptr = cnt + BN;                             // BN+1
    int* cursor  = row_ptr + BN + 1;                     // BN
    unsigned short* W1P = (unsigned short*)(cursor + BN);// 3*8*64*8
    unsigned short* W2P = W1P + 3 * 8 * 64 * 8;          // 3*64*64*8

    eae_zero_int<<<(BN + 255) / 256, 256, 0, stream>>>(cnt, BN);
    eae_hist_kernel<<<(E + 255) / 256, 256, 0, stream>>>(edge_dst, cnt, E);
    eae_scan_kernel<<<1, 256, 0, stream>>>(cnt, row_ptr, cursor, BN);
    eae_scatter_kernel<<<(E + 255) / 256, 256, 0, stream>>>(
        edge_dst, edge_src, edge_weight, edge_vec, cursor, edata, esrc, E);
    eae_pack_kernel<<<216, 64, 0, stream>>>(W1, W2, W1P, W2P);

    eae_init_kernel<<<BN, 128, 0, stream>>>(z, mask, absorber, z_emb, W_in, s, v);

    for (int blk = 0; blk < 3; ++blk) {
        eae_edge_kernel<<<512, 512, 0, stream>>>(
            row_ptr, edata, esrc,
            W1P + (size_t)blk * 8 * 64 * 8, b1 + (size_t)blk * 128,
            W2P + (size_t)blk * 64 * 64 * 8, b2 + (size_t)blk * 224,
            s, v, aggs, aggv, BN);
        eae_node_kernel<<<BN, 128, 0, stream>>>(Ws, Wv, Wg, alpha, s, v, aggs, aggv, blk);
    }
    eae_final_kernel<<<BN, 64, 0, stream>>>(mask, s, v, out);
}

// Round 8
// 426.646 us; speedup vs baseline: 1.6809x; 1.6809x over previous
//
#include <hip/hip_runtime.h>

#define CSC 64
#define CVC 32
#define HIDC 128
#define NWC 224
#define RBFD 32
#define CUTF 5.0f

typedef __attribute__((ext_vector_type(8))) short bfrag8;
typedef __attribute__((ext_vector_type(4))) float facc4;

__device__ __forceinline__ unsigned short f2bf(float x) {
    union { float f; unsigned int u; } a; a.f = x;
    unsigned int u = a.u;
    return (unsigned short)((u + 0x7fffu + ((u >> 16) & 1u)) >> 16);
}
__device__ __forceinline__ float bf2f(unsigned int u16) {
    union { float f; unsigned int v; } x; x.v = u16 << 16; return x.f;
}

__device__ __forceinline__ float siluf(float x) { return x / (1.0f + __expf(-x)); }
__device__ __forceinline__ float sigmf(float x) { return 1.0f / (1.0f + __expf(-x)); }

// ---------------- CSR build ------------------------------------------------------------------
__global__ __launch_bounds__(256) void eae_zero_int(int* __restrict__ p, int n) {
    int i = blockIdx.x * 256 + threadIdx.x;
    if (i < n) p[i] = 0;
}

__global__ __launch_bounds__(256) void eae_hist_kernel(const int* __restrict__ edge_dst,
                                                       int* __restrict__ cnt, int E) {
    int e = blockIdx.x * 256 + threadIdx.x;
    if (e < E) atomicAdd(&cnt[edge_dst[e]], 1);
}

__global__ __launch_bounds__(256) void eae_scan_kernel(const int* __restrict__ cnt,
                                                       int* __restrict__ row_ptr,
                                                       int* __restrict__ cursor, int BN) {
    __shared__ int part[256];
    int t = threadIdx.x;
    int per = (BN + 255) / 256;
    int base = t * per;
    int local[16];
    int lsum = 0;
    for (int i = 0; i < per; ++i) {
        int idx = base + i;
        int c = (idx < BN) ? cnt[idx] : 0;
        local[i] = c; lsum += c;
    }
    part[t] = lsum;
    __syncthreads();
    if (t == 0) {
        int run = 0;
        for (int i = 0; i < 256; ++i) { int v = part[i]; part[i] = run; run += v; }
    }
    __syncthreads();
    int run = part[t];
    for (int i = 0; i < per; ++i) {
        int idx = base + i;
        if (idx < BN) { row_ptr[idx] = run; cursor[idx] = run; run += local[i]; }
    }
    if (t == 255) row_ptr[BN] = run;
}

__global__ __launch_bounds__(256) void eae_scatter_kernel(
    const int* __restrict__ edge_dst, const int* __restrict__ edge_src,
    const float* __restrict__ edge_weight, const float* __restrict__ edge_vec,
    int* __restrict__ cursor, float4* __restrict__ edata, int* __restrict__ esrc, int E) {
    int e = blockIdx.x * 256 + threadIdx.x;
    if (e < E) {
        int pos = atomicAdd(&cursor[edge_dst[e]], 1);
        float4 d;
        d.x = edge_weight[e];
        d.y = edge_vec[3 * e + 0];
        d.z = edge_vec[3 * e + 1];
        d.w = edge_vec[3 * e + 2];
        edata[pos] = d;
        esrc[pos] = edge_src[e];
    }
}

// ---------------- weight packing: bf16 MFMA fragment layout (once per call) ------------------
__global__ __launch_bounds__(64) void eae_pack_kernel(
    const float* __restrict__ W1, const float* __restrict__ W2,
    unsigned short* __restrict__ W1P, unsigned short* __restrict__ W2P)
{
    int b = blockIdx.x;
    int lane = threadIdx.x;
    int t4 = lane >> 4, lr = lane & 15;
    if (b < 24) {
        int blk = b >> 3, mt = b & 7;
        const float* W1b = W1 + blk * 32 * 128;
        unsigned short* dst = W1P + ((size_t)b * 64 + lane) * 8;
        #pragma unroll
        for (int i = 0; i < 8; ++i) {
            int k = 8 * t4 + i;
            dst[i] = f2bf(W1b[k * HIDC + 16 * mt + lr]);
        }
    } else {
        int idx = b - 24;
        int blk = idx >> 6, rem = idx & 63;
        int mt = rem >> 2, ks = rem & 3;
        const float* W2b = W2 + blk * 128 * 224;
        unsigned short* dst = W2P + ((size_t)idx * 64 + lane) * 8;
        int ch = 16 * mt + lr;
        #pragma unroll
        for (int i = 0; i < 8; ++i) {
            int k = 32 * ks + 8 * t4 + i;
            dst[i] = (ch < NWC) ? f2bf(W2b[k * NWC + ch]) : (unsigned short)0;
        }
    }
}

// ---------------- init: s ; zero v (SoA) -----------------------------------------------------
__global__ __launch_bounds__(128) void eae_init_kernel(
    const int* __restrict__ z, const float* __restrict__ mask, const int* __restrict__ absorber,
    const float* __restrict__ z_emb, const float* __restrict__ W_in,
    float* __restrict__ s, float* __restrict__ v)
{
    int n = blockIdx.x;
    int t = threadIdx.x;
    int b = n >> 6;
    int ni = n & 63;
    float fm = mask[n];
    int zi = z[n];
    float af = (absorber[b] == ni) ? 1.0f : 0.0f;
    if (t < 64) {
        const float* ze = z_emb + zi * 64;
        float acc = 0.0f;
        #pragma unroll 4
        for (int k = 0; k < 64; ++k) acc += ze[k] * W_in[k * 64 + t];
        acc += af * W_in[64 * 64 + t];
        s[n * 64 + t] = acc * fm;
    }
    if (t < 96) v[n * 96 + t] = 0.0f;
}

// ---------------- K1: dense radial-MLP GEMM over all edges, store w (bf16) -------------------
// round-5-proven MFMA pipeline; epilogue replaced by coalesced-ish w store. No scattered reads.
__global__ __launch_bounds__(512) void eae_wgemm_kernel(
    const float4* __restrict__ edata,
    const unsigned short* __restrict__ W1Pb, const float* __restrict__ b1b,
    const unsigned short* __restrict__ W2Pb, const float* __restrict__ b2b,
    unsigned short* __restrict__ wbuf, int E, int ntiles)
{
    __shared__ unsigned short h_lds[64 * 128];   // h[e][k] bf16, swizzled, 16KB
    char* hb = (char*)h_lds;

    const int tid  = threadIdx.x;
    const int wid  = tid >> 6;       // 0..7
    const int lane = tid & 63;
    const int t4   = lane >> 4;
    const int lr   = lane & 15;
    const int swz  = (lr & 7) << 4;

    bfrag8 a1 = *reinterpret_cast<const bfrag8*>(W1Pb + ((size_t)wid * 64 + lane) * 8);
    float b1v[4];
    #pragma unroll
    for (int r = 0; r < 4; ++r) b1v[r] = b1b[16 * wid + 4 * t4 + r];

    bfrag8 a2[2][4];
    float b2v[2][4];
    #pragma unroll
    for (int m = 0; m < 2; ++m) {
        int mt = 2 * wid + m;
        #pragma unroll
        for (int ks = 0; ks < 4; ++ks)
            a2[m][ks] = *reinterpret_cast<const bfrag8*>(W2Pb + (((size_t)mt * 4 + ks) * 64 + lane) * 8);
        #pragma unroll
        for (int r = 0; r < 4; ++r) {
            int chr = 16 * mt + 4 * t4 + r;
            b2v[m][r] = (chr < NWC) ? b2b[chr] : 0.0f;
        }
    }

    const float delta = CUTF / (RBFD - 1);
    const float inv_delta = 1.0f / delta;
    const float PIF = 3.14159265358979323846f;

    for (int tile = blockIdx.x; tile < ntiles; tile += gridDim.x) {
        const int e0 = tile * 64;

        float env4[4];
        bfrag8 brbf[4];
        #pragma unroll
        for (int et = 0; et < 4; ++et) {
            int eg = e0 + 16 * et + lr;
            int ie = (eg < E) ? eg : (E - 1);
            float el = edata[ie].x;
            env4[et] = (el < CUTF) ? 0.5f * (__cosf(PIF * el / CUTF) + 1.0f) : 0.0f;
            float d = fminf(el, CUTF);
            bfrag8 f;
            #pragma unroll
            for (int i = 0; i < 8; ++i) {
                int k = 8 * t4 + i;
                float x = (d - (float)k * delta) * inv_delta;
                f[i] = (short)f2bf(__expf(-0.5f * x * x));
            }
            brbf[et] = f;
        }

        // GEMM1
        facc4 acc1[4];
        #pragma unroll
        for (int et = 0; et < 4; ++et) { facc4 zz = {0.f,0.f,0.f,0.f}; acc1[et] = zz; }
        #pragma unroll
        for (int et = 0; et < 4; ++et)
            acc1[et] = __builtin_amdgcn_mfma_f32_16x16x32_bf16(a1, brbf[et], acc1[et], 0, 0, 0);

        // silu -> LDS (swizzled)
        {
            int ch0b = (16 * wid + 4 * t4) * 2;
            #pragma unroll
            for (int et = 0; et < 4; ++et) {
                int e = 16 * et + lr;
                unsigned short hv[4];
                #pragma unroll
                for (int r = 0; r < 4; ++r)
                    hv[r] = f2bf(siluf(acc1[et][r] + b1v[r]));
                uint2 pk;
                pk.x = (unsigned int)hv[0] | ((unsigned int)hv[1] << 16);
                pk.y = (unsigned int)hv[2] | ((unsigned int)hv[3] << 16);
                *reinterpret_cast<uint2*>(hb + e * 256 + (ch0b ^ swz)) = pk;
            }
        }
        __syncthreads();

        // GEMM2
        facc4 acc2[2][4];
        #pragma unroll
        for (int m = 0; m < 2; ++m)
            #pragma unroll
            for (int et = 0; et < 4; ++et) { facc4 zz = {0.f,0.f,0.f,0.f}; acc2[m][et] = zz; }
        #pragma unroll
        for (int et = 0; et < 4; ++et) {
            int e = 16 * et + lr;
            bfrag8 hf[4];
            #pragma unroll
            for (int ks = 0; ks < 4; ++ks)
                hf[ks] = *reinterpret_cast<const bfrag8*>(hb + e * 256 + ((64 * ks + 16 * t4) ^ swz));
            #pragma unroll
            for (int m = 0; m < 2; ++m)
                #pragma unroll
                for (int ks = 0; ks < 4; ++ks)
                    acc2[m][et] = __builtin_amdgcn_mfma_f32_16x16x32_bf16(a2[m][ks], hf[ks], acc2[m][et], 0, 0, 0);
        }

        // store w = (acc2 + b2) * env, bf16
        #pragma unroll
        for (int m = 0; m < 2; ++m) {
            int mt = 2 * wid + m;
            if (mt < 14) {
                int cb = 16 * mt + 4 * t4;
                #pragma unroll
                for (int et = 0; et < 4; ++et) {
                    int eg = e0 + 16 * et + lr;
                    if (eg < E) {
                        unsigned short hv[4];
                        #pragma unroll
                        for (int r = 0; r < 4; ++r)
                            hv[r] = f2bf((acc2[m][et][r] + b2v[m][r]) * env4[et]);
                        uint2 pk;
                        pk.x = (unsigned int)hv[0] | ((unsigned int)hv[1] << 16);
                        pk.y = (unsigned int)hv[2] | ((unsigned int)hv[3] << 16);
                        *reinterpret_cast<uint2*>(wbuf + (size_t)eg * NWC + cb) = pk;
                    }
                }
            }
        }
        __syncthreads();
    }
}

// ---------------- K2: per-node gather + tensor-product + reduce (no MFMA, high occupancy) ----
// 256 threads = 4 waves per node; waves split the edge list; lane<56 owns 4 channels.
__global__ __launch_bounds__(256) void eae_gather_kernel(
    const int* __restrict__ row_ptr,
    const float4* __restrict__ edata, const int* __restrict__ esrc,
    const unsigned short* __restrict__ wbuf,
    const float* __restrict__ s, const float* __restrict__ v,
    float* __restrict__ aggs, float* __restrict__ aggv)
{
    __shared__ float sh[4][480];   // [wave][96 aggs | 384 aggv-SoA]

    const int n  = blockIdx.x;
    const int wq = threadIdx.x >> 6;
    const int l  = threadIdx.x & 63;
    const int ch0 = 4 * l;

    const float SQ3 = 1.7320508075688772f;
    const float IS3 = 0.57735026918962576f;
    const float IS2 = 0.70710678118654752f;

    const int ebeg = row_ptr[n];
    const int ecnt = row_ptr[n + 1] - ebeg;
    int per = (ecnt + 3) >> 2;
    int i0 = wq * per; if (i0 > ecnt) i0 = ecnt;
    int i1 = i0 + per; if (i1 > ecnt) i1 = ecnt;

    float a00=0.f,a01=0.f,a02=0.f, a10=0.f,a11=0.f,a12=0.f;
    float a20=0.f,a21=0.f,a22=0.f, a30=0.f,a31=0.f,a32=0.f;

    for (int i = i0; i < i1; ++i) {
        int ie = ebeg + i;
        float4 ed = edata[ie];
        float inv = 1.0f / fmaxf(ed.x, 1e-8f);
        float yx = SQ3 * ed.y * inv;
        float yy = SQ3 * ed.z * inv;
        float yz = SQ3 * ed.w * inv;
        int src = esrc[ie];

        float w0 = 0.f, w1 = 0.f, w2 = 0.f, w3 = 0.f;
        if (l < 56) {
            uint2 wp = *reinterpret_cast<const uint2*>(wbuf + (size_t)ie * NWC + ch0);
            w0 = bf2f(wp.x & 0xffffu); w1 = bf2f(wp.x >> 16);
            w2 = bf2f(wp.y & 0xffffu); w3 = bf2f(wp.y >> 16);
        }

        if (l < 16) {                       // w_ss: ch0 0..63
            float4 sv = *reinterpret_cast<const float4*>(&s[src * CSC + ch0]);
            a00 += w0 * sv.x; a10 += w1 * sv.y; a20 += w2 * sv.z; a30 += w3 * sv.w;
        } else if (l < 24) {                // w_vv: c 0..31
            int c = ch0 - 64;
            const float* vb = &v[src * 96];
            float4 vx4 = *reinterpret_cast<const float4*>(vb + c);
            float4 vy4 = *reinterpret_cast<const float4*>(vb + 32 + c);
            float4 vz4 = *reinterpret_cast<const float4*>(vb + 64 + c);
            a00 += w0 * (vx4.x * yx + vy4.x * yy + vz4.x * yz) * IS3;
            a10 += w1 * (vx4.y * yx + vy4.y * yy + vz4.y * yz) * IS3;
            a20 += w2 * (vx4.z * yx + vy4.z * yy + vz4.z * yz) * IS3;
            a30 += w3 * (vx4.w * yx + vy4.w * yy + vz4.w * yz) * IS3;
        } else if (l < 40) {                // w_sv: c 0..63
            int c = ch0 - 96;
            float4 sv = *reinterpret_cast<const float4*>(&s[src * CSC + c]);
            float t0 = w0 * sv.x, t1 = w1 * sv.y, t2 = w2 * sv.z, t3 = w3 * sv.w;
            a00 += t0 * yx; a01 += t0 * yy; a02 += t0 * yz;
            a10 += t1 * yx; a11 += t1 * yy; a12 += t1 * yz;
            a20 += t2 * yx; a21 += t2 * yy; a22 += t2 * yz;
            a30 += t3 * yx; a31 += t3 * yy; a32 += t3 * yz;
        } else if (l < 48) {                // w_vs: c 0..31
            int c = ch0 - 160;
            const float* vb = &v[src * 96];
            float4 vx4 = *reinterpret_cast<const float4*>(vb + c);
            float4 vy4 = *reinterpret_cast<const float4*>(vb + 32 + c);
            float4 vz4 = *reinterpret_cast<const float4*>(vb + 64 + c);
            a00 += w0 * vx4.x; a01 += w0 * vy4.x; a02 += w0 * vz4.x;
            a10 += w1 * vx4.y; a11 += w1 * vy4.y; a12 += w1 * vz4.y;
            a20 += w2 * vx4.z; a21 += w2 * vy4.z; a22 += w2 * vz4.z;
            a30 += w3 * vx4.w; a31 += w3 * vy4.w; a32 += w3 * vz4.w;
        } else if (l < 56) {                // w_vx: c 0..31 (cross / sqrt2)
            int c = ch0 - 192;
            const float* vb = &v[src * 96];
            float4 vx4 = *reinterpret_cast<const float4*>(vb + c);
            float4 vy4 = *reinterpret_cast<const float4*>(vb + 32 + c);
            float4 vz4 = *reinterpret_cast<const float4*>(vb + 64 + c);
            float s0 = w0 * IS2, s1 = w1 * IS2, s2 = w2 * IS2, s3 = w3 * IS2;
            a00 += s0 * (vy4.x * yz - vz4.x * yy); a01 += s0 * (vz4.x * yx - vx4.x * yz); a02 += s0 * (vx4.x * yy - vy4.x * yx);
            a10 += s1 * (vy4.y * yz - vz4.y * yy); a11 += s1 * (vz4.y * yx - vx4.y * yz); a12 += s1 * (vx4.y * yy - vy4.y * yx);
            a20 += s2 * (vy4.z * yz - vz4.z * yy); a21 += s2 * (vz4.z * yx - vx4.z * yz); a22 += s2 * (vx4.z * yy - vy4.z * yx);
            a30 += s3 * (vy4.w * yz - vz4.w * yy); a31 += s3 * (vz4.w * yx - vx4.w * yz); a32 += s3 * (vx4.w * yy - vy4.w * yx);
        }
    }

    // write per-wave partials into sh (flat layout: [0..95]=aggs, [96..479]=aggv SoA [3][128])
    float* shw = sh[wq];
    if (l < 16) {
        shw[ch0 + 0] = a00; shw[ch0 + 1] = a10; shw[ch0 + 2] = a20; shw[ch0 + 3] = a30;
    } else if (l < 24) {
        int c = ch0 - 64;
        shw[64 + c + 0] = a00; shw[64 + c + 1] = a10; shw[64 + c + 2] = a20; shw[64 + c + 3] = a30;
    } else if (l < 40) {
        int c = ch0 - 96;
        shw[96 + 0 * 128 + c + 0] = a00; shw[96 + 1 * 128 + c + 0] = a01; shw[96 + 2 * 128 + c + 0] = a02;
        shw[96 + 0 * 128 + c + 1] = a10; shw[96 + 1 * 128 + c + 1] = a11; shw[96 + 2 * 128 + c + 1] = a12;
        shw[96 + 0 * 128 + c + 2] = a20; shw[96 + 1 * 128 + c + 2] = a21; shw[96 + 2 * 128 + c + 2] = a22;
        shw[96 + 0 * 128 + c + 3] = a30; shw[96 + 1 * 128 + c + 3] = a31; shw[96 + 2 * 128 + c + 3] = a32;
    } else if (l < 48) {
        int c = 64 + (ch0 - 160);
        shw[96 + 0 * 128 + c + 0] = a00; shw[96 + 1 * 128 + c + 0] = a01; shw[96 + 2 * 128 + c + 0] = a02;
        shw[96 + 0 * 128 + c + 1] = a10; shw[96 + 1 * 128 + c + 1] = a11; shw[96 + 2 * 128 + c + 1] = a12;
        shw[96 + 0 * 128 + c + 2] = a20; shw[96 + 1 * 128 + c + 2] = a21; shw[96 + 2 * 128 + c + 2] = a22;
        shw[96 + 0 * 128 + c + 3] = a30; shw[96 + 1 * 128 + c + 3] = a31; shw[96 + 2 * 128 + c + 3] = a32;
    } else if (l < 56) {
        int c = 96 + (ch0 - 192);
        shw[96 + 0 * 128 + c + 0] = a00; shw[96 + 1 * 128 + c + 0] = a01; shw[96 + 2 * 128 + c + 0] = a02;
        shw[96 + 0 * 128 + c + 1] = a10; shw[96 + 1 * 128 + c + 1] = a11; shw[96 + 2 * 128 + c + 1] = a12;
        shw[96 + 0 * 128 + c + 2] = a20; shw[96 + 1 * 128 + c + 2] = a21; shw[96 + 2 * 128 + c + 2] = a22;
        shw[96 + 0 * 128 + c + 3] = a30; shw[96 + 1 * 128 + c + 3] = a31; shw[96 + 2 * 128 + c + 3] = a32;
    }
    __syncthreads();

    for (int i = threadIdx.x; i < 480; i += 256) {
        float sum = sh[0][i] + sh[1][i] + sh[2][i] + sh[3][i];
        if (i < 96) aggs[n * 96 + i] = sum;
        else        aggv[n * 384 + (i - 96)] = sum;
    }
}

// ---------------- node update (SoA v/aggv) ---------------------------------------------------
__global__ __launch_bounds__(128) void eae_node_kernel(
    const float* __restrict__ Ws, const float* __restrict__ Wv, const float* __restrict__ Wg,
    const float* __restrict__ alpha,
    float* __restrict__ s, float* __restrict__ v,
    const float* __restrict__ aggs, const float* __restrict__ aggv, int blk)
{
    int n = blockIdx.x;
    int t = threadIdx.x;
    __shared__ float sh_as[96];
    __shared__ float sh_av[384];
    __shared__ float sh_us[64];
    __shared__ float sh_g[32];

    for (int i = t; i < 96; i += 128) sh_as[i] = aggs[n * 96 + i];
    for (int i = t; i < 384; i += 128) sh_av[i] = aggv[n * 384 + i];
    __syncthreads();

    float a = alpha[blk];
    const float* Wsb = Ws + blk * 96 * 64;
    const float* Wvb = Wv + blk * 128 * 32;
    const float* Wgb = Wg + blk * 64 * 32;

    if (t < 64) {
        float acc = 0.0f;
        #pragma unroll 4
        for (int j = 0; j < 96; ++j) acc += sh_as[j] * Wsb[j * 64 + t];
        sh_us[t] = siluf(acc);
    }
    __syncthreads();
    if (t < 32) {
        float acc = 0.0f;
        #pragma unroll 4
        for (int j = 0; j < 64; ++j) acc += sh_us[j] * Wgb[j * 32 + t];
        sh_g[t] = sigmf(acc);
    }
    if (t < 64) s[n * 64 + t] += a * sh_us[t];
    __syncthreads();
    if (t < 96) {
        int d = t >> 5;
        int c = t & 31;
        float acc = 0.0f;
        #pragma unroll 4
        for (int j = 0; j < 128; ++j) acc += sh_av[d * 128 + j] * Wvb[j * 32 + c];
        v[n * 96 + d * 32 + c] += a * sh_g[c] * acc;
    }
}

// ---------------- final: IrrepNorm + mask + pack output --------------------------------------
__global__ __launch_bounds__(64) void eae_final_kernel(
    const float* __restrict__ mask, const float* __restrict__ s, const float* __restrict__ v,
    float* __restrict__ out)
{
    int n = blockIdx.x;
    int t = threadIdx.x;
    float fm = mask[n];

    float sv = s[n * 64 + t];
    float ss = sv * sv;
    #pragma unroll
    for (int o = 32; o >= 1; o >>= 1) ss += __shfl_xor(ss, o);
    float sn = sv / sqrtf(ss / 64.0f + 1e-6f);
    out[n * 160 + t] = sn * fm;

    float vx = (t < 32) ? v[n * 96 + t]      : 0.0f;
    float vy = (t < 32) ? v[n * 96 + 32 + t] : 0.0f;
    float vz = (t < 32) ? v[n * 96 + 64 + t] : 0.0f;
    float vs2 = vx * vx + vy * vy + vz * vz;
    #pragma unroll
    for (int o = 32; o >= 1; o >>= 1) vs2 += __shfl_xor(vs2, o);
    float scale = fm / sqrtf(vs2 / 32.0f + 1e-6f);
    if (t < 32) {
        out[n * 160 + 64 + t * 3 + 0] = vx * scale;
        out[n * 160 + 64 + t * 3 + 1] = vy * scale;
        out[n * 160 + 64 + t * 3 + 2] = vz * scale;
    }
}

extern "C" void kernel_launch(void* const* d_in, const int* in_sizes, int n_in,
                              void* d_out, int out_size, void* d_ws, size_t ws_size,
                              hipStream_t stream) {
    const int*   z           = (const int*)d_in[0];
    const float* mask        = (const float*)d_in[1];
    const int*   absorber    = (const int*)d_in[2];
    const int*   edge_src    = (const int*)d_in[3];
    const int*   edge_dst    = (const int*)d_in[4];
    const float* edge_weight = (const float*)d_in[5];
    const float* edge_vec    = (const float*)d_in[6];
    const float* z_emb       = (const float*)d_in[7];
    const float* W_in        = (const float*)d_in[8];
    const float* W1          = (const float*)d_in[9];
    const float* b1          = (const float*)d_in[10];
    const float* W2          = (const float*)d_in[11];
    const float* b2          = (const float*)d_in[12];
    const float* Ws          = (const float*)d_in[13];
    const float* Wv          = (const float*)d_in[14];
    const float* Wg          = (const float*)d_in[15];
    const float* alpha       = (const float*)d_in[16];
    float* out = (float*)d_out;

    const int BN = in_sizes[0];    // 2048
    const int E  = in_sizes[3];    // 131072

    float* ws_f = (float*)d_ws;
    float4* edata = (float4*)ws_f;                        // E float4
    float* s    = ws_f + (size_t)E * 4;                   // BN*64
    float* v    = s + (size_t)BN * 64;                    // BN*96  SoA [3][32]
    float* aggs = v + (size_t)BN * 96;                    // BN*96
    float* aggv = aggs + (size_t)BN * 96;                 // BN*384 SoA [3][128]
    int*   iws  = (int*)(aggv + (size_t)BN * 384);
    int* esrc    = iws;                                   // E
    int* cnt     = esrc + E;                              // BN
    int* row_ptr = cnt + BN;                              // BN+2 (pad for 8B align below)
    int* cursor  = row_ptr + BN + 2;                      // BN
    unsigned short* W1P = (unsigned short*)(cursor + BN); // 3*8*64*8   (8B-aligned)
    unsigned short* W2P = W1P + 3 * 8 * 64 * 8;           // 3*64*64*8
    unsigned short* wbuf = W2P + 3 * 64 * 64 * 8;         // E*224 bf16 (~59 MB)

    eae_zero_int<<<(BN + 255) / 256, 256, 0, stream>>>(cnt, BN);
    eae_hist_kernel<<<(E + 255) / 256, 256, 0, stream>>>(edge_dst, cnt, E);
    eae_scan_kernel<<<1, 256, 0, stream>>>(cnt, row_ptr, cursor, BN);
    eae_scatter_kernel<<<(E + 255) / 256, 256, 0, stream>>>(
        edge_dst, edge_src, edge_weight, edge_vec, cursor, edata, esrc, E);
    eae_pack_kernel<<<216, 64, 0, stream>>>(W1, W2, W1P, W2P);

    eae_init_kernel<<<BN, 128, 0, stream>>>(z, mask, absorber, z_emb, W_in, s, v);

    int ntiles = (E + 63) / 64;
    for (int blk = 0; blk < 3; ++blk) {
        eae_wgemm_kernel<<<512, 512, 0, stream>>>(
            edata,
            W1P + (size_t)blk * 8 * 64 * 8, b1 + (size_t)blk * 128,
            W2P + (size_t)blk * 64 * 64 * 8, b2 + (size_t)blk * 224,
            wbuf, E, ntiles);
        eae_gather_kernel<<<BN, 256, 0, stream>>>(
            row_ptr, edata, esrc, wbuf, s, v, aggs, aggv);
        eae_node_kernel<<<BN, 128, 0, stream>>>(Ws, Wv, Wg, alpha, s, v, aggs, aggv, blk);
    }
    eae_final_kernel<<<BN, 64, 0, stream>>>(mask, s, v, out);
}